// Round 3
// baseline (231.014 us; speedup 1.0000x reference)
//
#include <hip/hip_runtime.h>
#include <math.h>

#define BB 32
#define TT 4096
#define FF 256
#define CH 64              // timesteps per K1 block
#define NC (TT / CH)       // 64 chunks per batch
#define K_TOP 409          // int(4096 * 0.1)
#define EMPH_HALF 0.5f     // (1.5 - 1.0)

__device__ __forceinline__ unsigned flip_key(float v) {
    unsigned u = __float_as_uint(v);
    return (u & 0x80000000u) ? ~u : (u | 0x80000000u);
}
__device__ __forceinline__ float unflip_key(unsigned k) {
    unsigned u = (k & 0x80000000u) ? (k & 0x7fffffffu) : ~k;
    return __uint_as_float(u);
}
// fast tanh: (e^{2z}-1)/(e^{2z}+1), clamped so e^{2z} never overflows
__device__ __forceinline__ float fast_tanh(float z) {
    z = fminf(fmaxf(z, -15.f), 15.f);
    const float t = __expf(2.f * z);
    return (t - 1.f) * __builtin_amdgcn_rcpf(t + 1.f);
}

// ---------------------------------------------------------------------------
// K1: fused scores + online-softmax chunk partials. ONE HBM pass over x.
// grid = B*NC blocks of 256 (4 waves). Each wave owns 4 rows per 16-row
// sub-tile and keeps a PRIVATE online-softmax state (no per-tile syncs);
// the 4 wave-partials merge once at the end.
// Outputs: e[B*T], P[B*NC*F] = sum_t exp(e-m_c) x, cm[B*NC], cs[B*NC].
// ---------------------------------------------------------------------------
__global__ __launch_bounds__(256) void fused_pass1(const float* __restrict__ x,
                                                   const float* __restrict__ W,
                                                   const float* __restrict__ bias,
                                                   float* __restrict__ e,
                                                   float* __restrict__ P,
                                                   float* __restrict__ cm,
                                                   float* __restrict__ cs) {
    const int b = blockIdx.x / NC;
    const int c = blockIdx.x % NC;
    const int tid = threadIdx.x;
    const int wv = tid >> 6, ln = tid & 63;

    const float* xc = x + ((size_t)b * TT + (size_t)c * CH) * FF;
    const float4 wvec = ((const float4*)W)[ln];
    const float  bb   = bias[0];

    float4 acc = make_float4(0.f, 0.f, 0.f, 0.f);
    float  m = -1e30f, ssum = 0.f;

    #pragma unroll
    for (int s0 = 0; s0 < CH; s0 += 16) {
        const int r0 = s0 + wv * 4;             // this wave's 4 rows
        float4 xr[4];
        #pragma unroll
        for (int i = 0; i < 4; i++)
            xr[i] = ((const float4*)(xc + (size_t)(r0 + i) * FF))[ln];

        float dv[4];
        #pragma unroll
        for (int i = 0; i < 4; i++)
            dv[i] = xr[i].x * wvec.x + xr[i].y * wvec.y +
                    xr[i].z * wvec.z + xr[i].w * wvec.w;
        #pragma unroll
        for (int i = 0; i < 4; i++) {
            float d = dv[i];
            #pragma unroll
            for (int off = 32; off; off >>= 1) d += __shfl_xor(d, off);
            dv[i] = fast_tanh(d + bb);          // all 64 lanes hold the score
        }
        if (ln == 0)
            *(float4*)(e + (size_t)b * TT + c * CH + r0) =
                make_float4(dv[0], dv[1], dv[2], dv[3]);

        // private online-softmax update (registers only, no sync)
        float lm = m;
        #pragma unroll
        for (int i = 0; i < 4; i++) lm = fmaxf(lm, dv[i]);
        const float alpha = __expf(m - lm);
        acc.x *= alpha; acc.y *= alpha; acc.z *= alpha; acc.w *= alpha;
        ssum *= alpha;
        #pragma unroll
        for (int i = 0; i < 4; i++) {
            const float wgt = __expf(dv[i] - lm);
            ssum += wgt;
            acc.x += wgt * xr[i].x; acc.y += wgt * xr[i].y;
            acc.z += wgt * xr[i].z; acc.w += wgt * xr[i].w;
        }
        m = lm;
    }

    // ---- merge the 4 per-wave partials (single sync) ----
    __shared__ float4 part4[4][64];
    __shared__ float sm[4], ss4[4];
    part4[wv][ln] = acc;
    if (ln == 0) { sm[wv] = m; ss4[wv] = ssum; }
    __syncthreads();

    const float m0 = sm[0], m1 = sm[1], m2 = sm[2], m3 = sm[3];
    const float mc = fmaxf(fmaxf(m0, m1), fmaxf(m2, m3));
    const float s0s = __expf(m0 - mc), s1s = __expf(m1 - mc);
    const float s2s = __expf(m2 - mc), s3s = __expf(m3 - mc);
    const float* pf = (const float*)part4;      // [4][256] floats
    const float p = pf[tid] * s0s + pf[256 + tid] * s1s +
                    pf[512 + tid] * s2s + pf[768 + tid] * s3s;
    P[((size_t)b * NC + c) * FF + tid] = p;
    if (tid == 0) {
        cm[b * NC + c] = mc;
        cs[b * NC + c] = ss4[0] * s0s + ss4[1] * s1s + ss4[2] * s2s + ss4[3] * s3s;
    }
}

// ---------------------------------------------------------------------------
// K2: per-batch everything-else, one block (256 threads) per batch:
//   A) gmax/Z from chunk (m,s)
//   B) ballot-based radix select of the K_TOP-th largest score key
//   C) combine chunk partials  sum_c P[c,f]*e^{m_c-gmax}
//   D) gather top-k rows, add 0.5*e^{e_t-gmax}*x[t,f]
//   E) out[b,f] = acc / Z   (direct store — no zero-init, no atomics)
// ---------------------------------------------------------------------------
__global__ __launch_bounds__(256) void select_combine(const float* __restrict__ x,
                                                      const float* __restrict__ e,
                                                      const float* __restrict__ P,
                                                      const float* __restrict__ cm,
                                                      const float* __restrict__ cs,
                                                      float* __restrict__ out) {
    const int b = blockIdx.x;
    const int tid = threadIdx.x;
    const int wv = tid >> 6, ln = tid & 63;

    __shared__ float sgm, sZ;
    __shared__ int   sc4[4];
    __shared__ float sscale[NC];
    __shared__ int   scount;
    __shared__ int   slist[TT];
    __shared__ float sval[TT];

    // ---- A: global max + Z over NC=64 chunks (wave 0) ----
    if (tid < 64) {
        const float mm = cm[b * NC + tid];
        const float ss = cs[b * NC + tid];
        float g = mm;
        #pragma unroll
        for (int off = 32; off; off >>= 1) g = fmaxf(g, __shfl_xor(g, off));
        float zz = ss * __expf(mm - g);
        #pragma unroll
        for (int off = 32; off; off >>= 1) zz += __shfl_xor(zz, off);
        if (tid == 0) { sgm = g; sZ = zz; scount = 0; }
    }

    // ---- keys for the radix select ----
    const float* eb = e + (size_t)b * TT;
    unsigned key[16];
    #pragma unroll
    for (int j = 0; j < 16; j++) key[j] = flip_key(eb[tid + 256 * j]);
    __syncthreads();
    if (tid < 64) sscale[tid] = __expf(cm[b * NC + tid] - sgm);

    // ---- B: MSB-first radix select (ballot counting) ----
    unsigned prefix = 0u, mask = 0u;
    int kk = K_TOP;
    for (int bit = 31; bit >= 0; bit--) {
        const unsigned bm = 1u << bit;
        const unsigned m2 = mask | bm;
        const unsigned want = prefix | bm;
        int cnt = 0;
        #pragma unroll
        for (int j = 0; j < 16; j++)
            cnt += (int)__popcll(__ballot((key[j] & m2) == want));
        __syncthreads();                 // previous iteration's sc4 reads done
        if (ln == 0) sc4[wv] = cnt;
        __syncthreads();
        const int tot = sc4[0] + sc4[1] + sc4[2] + sc4[3];
        if (tot >= kk) prefix = want; else kk -= tot;
        mask = m2;
    }
    const unsigned Kkey = prefix;

    // ---- C: combine chunk partials (thread tid owns feature tid) ----
    float acc = 0.f;
    #pragma unroll 4
    for (int c = 0; c < NC; c++)
        acc += P[((size_t)b * NC + c) * FF + tid] * sscale[c];

    // ---- D: top-k gather ----
    #pragma unroll
    for (int j = 0; j < 16; j++) {
        if (key[j] >= Kkey) {
            const int i = atomicAdd(&scount, 1);
            slist[i] = tid + 256 * j;
            sval[i]  = unflip_key(key[j]);
        }
    }
    __syncthreads();
    const int n = scount;
    for (int i = tid; i < n; i += 256)
        sval[i] = EMPH_HALF * __expf(sval[i] - sgm);
    __syncthreads();

    const float* xb = x + (size_t)b * TT * FF;
    for (int i = 0; i < n; i++)
        acc += sval[i] * xb[(size_t)slist[i] * FF + tid];

    // ---- E: direct store ----
    out[b * FF + tid] = acc * (1.f / sZ);
}

// ---------------------------------------------------------------------------
extern "C" void kernel_launch(void* const* d_in, const int* in_sizes, int n_in,
                              void* d_out, int out_size, void* d_ws, size_t ws_size,
                              hipStream_t stream) {
    const float* x    = (const float*)d_in[0];   // [B,T,F]
    const float* W    = (const float*)d_in[1];   // [F,1]
    const float* bias = (const float*)d_in[2];   // [1]
    float* out = (float*)d_out;                  // [B,1,F]

    float* e     = (float*)d_ws;                 // B*T
    float* P     = e + (size_t)BB * TT;          // B*NC*F
    float* cm    = P + (size_t)BB * NC * FF;     // B*NC
    float* cs    = cm + BB * NC;                 // B*NC

    fused_pass1<<<BB * NC, 256, 0, stream>>>(x, W, bias, e, P, cm, cs);
    select_combine<<<BB, 256, 0, stream>>>(x, e, P, cm, cs, out);
}

// Round 4
// 209.695 us; speedup vs baseline: 1.1017x; 1.1017x over previous
//
#include <hip/hip_runtime.h>
#include <math.h>

#define BB 32
#define TT 4096
#define FF 256
#define CH 64              // timesteps per K1 block
#define NC (TT / CH)       // 64 chunks per batch
#define K_TOP 409          // int(4096 * 0.1)
#define EMPH_HALF 0.5f     // (1.5 - 1.0)
#define NSEG 16            // K3 segments per batch (256 timesteps each)
#define SEGT (TT / NSEG)   // 256
#define CPS (NC / NSEG)    // 4 chunks per segment

__device__ __forceinline__ unsigned flip_key(float v) {
    unsigned u = __float_as_uint(v);
    return (u & 0x80000000u) ? ~u : (u | 0x80000000u);
}
__device__ __forceinline__ float unflip_key(unsigned k) {
    unsigned u = (k & 0x80000000u) ? (k & 0x7fffffffu) : ~k;
    return __uint_as_float(u);
}
// fast tanh: (e^{2z}-1)/(e^{2z}+1), clamped so e^{2z} never overflows
__device__ __forceinline__ float fast_tanh(float z) {
    z = fminf(fmaxf(z, -15.f), 15.f);
    const float t = __expf(2.f * z);
    return (t - 1.f) * __builtin_amdgcn_rcpf(t + 1.f);
}

// ---------------------------------------------------------------------------
// K1: fused scores + online-softmax chunk partials. ONE HBM pass over x.
// grid = B*NC blocks of 256 (4 waves). Each wave owns 4 rows per 16-row
// sub-tile with a PRIVATE online-softmax state (no inner syncs); the 4
// wave-partials merge once at the end.
// Outputs: e[B*T], P[B*NC*F] = sum_t exp(e-m_c) x, cm[B*NC], cs[B*NC].
// ---------------------------------------------------------------------------
__global__ __launch_bounds__(256) void fused_pass1(const float* __restrict__ x,
                                                   const float* __restrict__ W,
                                                   const float* __restrict__ bias,
                                                   float* __restrict__ e,
                                                   float* __restrict__ P,
                                                   float* __restrict__ cm,
                                                   float* __restrict__ cs) {
    const int b = blockIdx.x / NC;
    const int c = blockIdx.x % NC;
    const int tid = threadIdx.x;
    const int wv = tid >> 6, ln = tid & 63;

    const float* xc = x + ((size_t)b * TT + (size_t)c * CH) * FF;
    const float4 wvec = ((const float4*)W)[ln];
    const float  bb   = bias[0];

    float4 acc = make_float4(0.f, 0.f, 0.f, 0.f);
    float  m = -1e30f, ssum = 0.f;

    #pragma unroll
    for (int s0 = 0; s0 < CH; s0 += 16) {
        const int r0 = s0 + wv * 4;             // this wave's 4 rows
        float4 xr[4];
        #pragma unroll
        for (int i = 0; i < 4; i++)
            xr[i] = ((const float4*)(xc + (size_t)(r0 + i) * FF))[ln];

        float dv[4];
        #pragma unroll
        for (int i = 0; i < 4; i++)
            dv[i] = xr[i].x * wvec.x + xr[i].y * wvec.y +
                    xr[i].z * wvec.z + xr[i].w * wvec.w;
        #pragma unroll
        for (int i = 0; i < 4; i++) {
            float d = dv[i];
            #pragma unroll
            for (int off = 32; off; off >>= 1) d += __shfl_xor(d, off);
            dv[i] = fast_tanh(d + bb);          // all 64 lanes hold the score
        }
        if (ln == 0)
            *(float4*)(e + (size_t)b * TT + c * CH + r0) =
                make_float4(dv[0], dv[1], dv[2], dv[3]);

        // private online-softmax update (registers only, no sync)
        float lm = m;
        #pragma unroll
        for (int i = 0; i < 4; i++) lm = fmaxf(lm, dv[i]);
        const float alpha = __expf(m - lm);
        acc.x *= alpha; acc.y *= alpha; acc.z *= alpha; acc.w *= alpha;
        ssum *= alpha;
        #pragma unroll
        for (int i = 0; i < 4; i++) {
            const float wgt = __expf(dv[i] - lm);
            ssum += wgt;
            acc.x += wgt * xr[i].x; acc.y += wgt * xr[i].y;
            acc.z += wgt * xr[i].z; acc.w += wgt * xr[i].w;
        }
        m = lm;
    }

    // ---- merge the 4 per-wave partials (single sync) ----
    __shared__ float4 part4[4][64];
    __shared__ float sm[4], ss4[4];
    part4[wv][ln] = acc;
    if (ln == 0) { sm[wv] = m; ss4[wv] = ssum; }
    __syncthreads();

    const float m0 = sm[0], m1 = sm[1], m2 = sm[2], m3 = sm[3];
    const float mc = fmaxf(fmaxf(m0, m1), fmaxf(m2, m3));
    const float s0s = __expf(m0 - mc), s1s = __expf(m1 - mc);
    const float s2s = __expf(m2 - mc), s3s = __expf(m3 - mc);
    const float* pf = (const float*)part4;      // [4][256] floats
    const float p = pf[tid] * s0s + pf[256 + tid] * s1s +
                    pf[512 + tid] * s2s + pf[768 + tid] * s3s;
    P[((size_t)b * NC + c) * FF + tid] = p;
    if (tid == 0) {
        cm[b * NC + c] = mc;
        cs[b * NC + c] = ss4[0] * s0s + ss4[1] * s1s + ss4[2] * s2s + ss4[3] * s3s;
    }
}

// ---------------------------------------------------------------------------
// K2: per-batch stats, one block per batch. gmax/Z from chunk (m,s);
// ballot-based radix select of the K_TOP-th largest score key.
// Also zeros out[b,:] (runs before K3's atomics in stream order).
// stats[b] = {gmax, Z, Kkey-bits}.
// ---------------------------------------------------------------------------
__global__ __launch_bounds__(256) void select_kernel(const float* __restrict__ e,
                                                     const float* __restrict__ cm,
                                                     const float* __restrict__ cs,
                                                     float* __restrict__ stats,
                                                     float* __restrict__ out) {
    const int b = blockIdx.x;
    const int tid = threadIdx.x;
    const int wv = tid >> 6, ln = tid & 63;

    out[b * FF + tid] = 0.f;                    // zero for K3's atomicAdd

    __shared__ float sgm, sZ;
    __shared__ int   sc4[4];

    // ---- gmax + Z over NC=64 chunks (wave 0) ----
    if (tid < 64) {
        const float mm = cm[b * NC + tid];
        const float ss = cs[b * NC + tid];
        float g = mm;
        #pragma unroll
        for (int off = 32; off; off >>= 1) g = fmaxf(g, __shfl_xor(g, off));
        float zz = ss * __expf(mm - g);
        #pragma unroll
        for (int off = 32; off; off >>= 1) zz += __shfl_xor(zz, off);
        if (tid == 0) { sgm = g; sZ = zz; }
    }

    const float* eb = e + (size_t)b * TT;
    unsigned key[16];
    #pragma unroll
    for (int j = 0; j < 16; j++) key[j] = flip_key(eb[tid + 256 * j]);

    // ---- MSB-first radix select (ballot counting) ----
    unsigned prefix = 0u, mask = 0u;
    int kk = K_TOP;
    for (int bit = 31; bit >= 0; bit--) {
        const unsigned bm = 1u << bit;
        const unsigned m2 = mask | bm;
        const unsigned want = prefix | bm;
        int cnt = 0;
        #pragma unroll
        for (int j = 0; j < 16; j++)
            cnt += (int)__popcll(__ballot((key[j] & m2) == want));
        __syncthreads();                 // previous iteration's sc4 reads done
        if (ln == 0) sc4[wv] = cnt;
        __syncthreads();
        const int tot = sc4[0] + sc4[1] + sc4[2] + sc4[3];
        if (tot >= kk) prefix = want; else kk -= tot;
        mask = m2;
    }

    if (tid == 0) {
        stats[3 * b + 0] = sgm;
        stats[3 * b + 1] = sZ;
        stats[3 * b + 2] = __uint_as_float(prefix);
    }
}

// ---------------------------------------------------------------------------
// K3: parallel combine + top-k emphasis gather.
// grid = B*NSEG = 512 blocks of 256; block (b,s) handles chunks 4s..4s+3 and
// timesteps [s*256, (s+1)*256). Thread tid owns feature tid.
// out[b,f] += ( sum_c P*e^{m_c-gmax} + 0.5*sum_{topk t} e^{e_t-gmax} x ) / Z
// ---------------------------------------------------------------------------
__global__ __launch_bounds__(256) void combine_kernel(const float* __restrict__ x,
                                                      const float* __restrict__ e,
                                                      const float* __restrict__ P,
                                                      const float* __restrict__ cm,
                                                      const float* __restrict__ stats,
                                                      float* __restrict__ out) {
    const int b = blockIdx.x / NSEG;
    const int s = blockIdx.x % NSEG;
    const int tid = threadIdx.x;

    const float gmax = stats[3 * b + 0];
    const float Z    = stats[3 * b + 1];
    const unsigned Kkey = __float_as_uint(stats[3 * b + 2]);

    float acc = 0.f;
    #pragma unroll
    for (int c = 0; c < CPS; c++) {
        const int cc = s * CPS + c;
        const float sc2 = __expf(cm[b * NC + cc] - gmax);
        acc += P[((size_t)b * NC + cc) * FF + tid] * sc2;
    }

    __shared__ int scount;
    __shared__ int slist[SEGT];
    __shared__ float sval[SEGT];
    if (tid == 0) scount = 0;
    __syncthreads();

    const int t = s * SEGT + tid;
    const float ev = e[(size_t)b * TT + t];
    if (flip_key(ev) >= Kkey) {
        const int i = atomicAdd(&scount, 1);
        slist[i] = t;
        sval[i] = EMPH_HALF * __expf(ev - gmax);
    }
    __syncthreads();

    const int n = scount;
    const float* xb = x + (size_t)b * TT * FF;
    for (int i = 0; i < n; i++)
        acc += sval[i] * xb[(size_t)slist[i] * FF + tid];

    atomicAdd(&out[b * FF + tid], acc * (1.f / Z));
}

// ---------------------------------------------------------------------------
extern "C" void kernel_launch(void* const* d_in, const int* in_sizes, int n_in,
                              void* d_out, int out_size, void* d_ws, size_t ws_size,
                              hipStream_t stream) {
    const float* x    = (const float*)d_in[0];   // [B,T,F]
    const float* W    = (const float*)d_in[1];   // [F,1]
    const float* bias = (const float*)d_in[2];   // [1]
    float* out = (float*)d_out;                  // [B,1,F]

    float* e     = (float*)d_ws;                 // B*T
    float* P     = e + (size_t)BB * TT;          // B*NC*F
    float* cm    = P + (size_t)BB * NC * FF;     // B*NC
    float* cs    = cm + BB * NC;                 // B*NC
    float* stats = cs + BB * NC;                 // 3*B

    fused_pass1<<<BB * NC, 256, 0, stream>>>(x, W, bias, e, P, cm, cs);
    select_kernel<<<BB, 256, 0, stream>>>(e, cm, cs, stats, out);
    combine_kernel<<<BB * NSEG, 256, 0, stream>>>(x, e, P, cm, stats, out);
}